// Round 5
// baseline (371.449 us; speedup 1.0000x reference)
//
#include <hip/hip_runtime.h>
#include <hip/hip_bf16.h>
#include <math.h>

// MMCL hard-negative loss, MI355X.
// Per row: pos = x[t]; top-K (K=655) values of row excluding col t;
// loss = -(10*pos - logsumexp([10*pos,10*pos,10*hn_k])); output = mean over rows.
//
// One streaming pass/row filters candidates > T=2.0 into LDS (E~1491 of
// 65535 for N(0,1)), exact 4-round radix select in LDS for the K-th largest
// (tie-exact), exp-sum from LDS. Exact global-memory radix-select fallback
// if the filter under/overflows (never expected on this data).

#define BLK 256
#define CAP 8192   // LDS candidate capacity (32 KB)

__device__ __forceinline__ unsigned ordkey(float f) {
    // order-preserving map: larger float <-> larger unsigned
    unsigned u = __float_as_uint(f);
    return (u & 0x80000000u) ? ~u : (u | 0x80000000u);
}
__device__ __forceinline__ float keyval(unsigned k) {
    unsigned u = (k & 0x80000000u) ? (k & 0x7FFFFFFFu) : ~k;
    return __uint_as_float(u);
}

__global__ __launch_bounds__(BLK) void row_loss_kernel(
    const float* __restrict__ logits,
    const int* __restrict__ targets,
    float* __restrict__ row_loss,
    int N, int K)
{
    const int row = blockIdx.x;
    const int tid = threadIdx.x;
    const float* __restrict__ x = logits + (size_t)row * (size_t)N;
    const int t = targets[row];

    __shared__ float    s_cand[CAP];
    __shared__ unsigned s_hist[256];
    __shared__ unsigned s_scan[256];
    __shared__ float    s_red[BLK];
    __shared__ int      s_cnt;
    __shared__ float    s_pos;
    __shared__ unsigned s_digit, s_newrem;

    if (tid == 0) { s_cnt = 0; s_pos = x[t]; }
    __syncthreads();

    // ---- pass 1: stream row; track max over i != t; spill candidates > T to LDS
    const float T = 2.0f;
    float lmax = -INFINITY;
    const int N4 = N >> 2;
    const int jt = t >> 2;           // the one float4 containing column t
    const float4* __restrict__ x4 = (const float4*)x;
    #pragma unroll 2
    for (int j = tid; j < N4; j += BLK) {
        float4 v = x4[j];
        if (j == jt) {               // rare: handle exclusion per-element
            const int et = t & 3;
            float vv[4] = {v.x, v.y, v.z, v.w};
            #pragma unroll
            for (int e = 0; e < 4; ++e) {
                if (e == et) continue;
                lmax = fmaxf(lmax, vv[e]);
                if (vv[e] > T) { int p = atomicAdd(&s_cnt, 1); if (p < CAP) s_cand[p] = vv[e]; }
            }
        } else {
            lmax = fmaxf(lmax, fmaxf(fmaxf(v.x, v.y), fmaxf(v.z, v.w)));
            if (v.x > T) { int p = atomicAdd(&s_cnt, 1); if (p < CAP) s_cand[p] = v.x; }
            if (v.y > T) { int p = atomicAdd(&s_cnt, 1); if (p < CAP) s_cand[p] = v.y; }
            if (v.z > T) { int p = atomicAdd(&s_cnt, 1); if (p < CAP) s_cand[p] = v.z; }
            if (v.w > T) { int p = atomicAdd(&s_cnt, 1); if (p < CAP) s_cand[p] = v.w; }
        }
    }
    for (int i = (N4 << 2) + tid; i < N; i += BLK) {   // tail (N%4 != 0)
        if (i != t) { float v = x[i]; lmax = fmaxf(lmax, v); if (v > T) { int p = atomicAdd(&s_cnt, 1); if (p < CAP) s_cand[p] = v; } }
    }

    // max reduce (maxhn = max over i != t)
    s_red[tid] = lmax;
    __syncthreads();
    for (int s = BLK >> 1; s > 0; s >>= 1) {
        if (tid < s) s_red[tid] = fmaxf(s_red[tid], s_red[tid + s]);
        __syncthreads();
    }
    const float maxhn = s_red[0];
    const int cnt = s_cnt;
    const float m = 10.0f * fmaxf(s_pos, maxhn);
    const bool fast = (cnt >= K && cnt <= CAP);   // uniform across block

    // ---- exact radix select for K-th largest (MSB-first, 8-bit digits)
    unsigned prefix = 0, rem = (unsigned)K;
    for (int round = 0; round < 4; ++round) {
        const int shift = 24 - 8 * round;
        s_hist[tid] = 0;
        __syncthreads();
        if (fast) {
            for (int i = tid; i < cnt; i += BLK) {
                unsigned key = ordkey(s_cand[i]);
                if (round == 0 || (key >> (shift + 8)) == prefix)
                    atomicAdd(&s_hist[(key >> shift) & 255u], 1u);
            }
        } else {
            for (int j = tid; j < N4; j += BLK) {
                float4 v = x4[j];
                int i0 = j << 2;
                float vv[4] = {v.x, v.y, v.z, v.w};
                #pragma unroll
                for (int e = 0; e < 4; ++e) {
                    if (i0 + e == t) continue;
                    unsigned key = ordkey(vv[e]);
                    if (round == 0 || (key >> (shift + 8)) == prefix)
                        atomicAdd(&s_hist[(key >> shift) & 255u], 1u);
                }
            }
            for (int i = (N4 << 2) + tid; i < N; i += BLK) {
                if (i == t) continue;
                unsigned key = ordkey(x[i]);
                if (round == 0 || (key >> (shift + 8)) == prefix)
                    atomicAdd(&s_hist[(key >> shift) & 255u], 1u);
            }
        }
        __syncthreads();
        // parallel suffix sum over the 256 bins: s_scan[d] = sum(hist[d..255])
        const unsigned mine = s_hist[tid];
        s_scan[tid] = mine;
        __syncthreads();
        #pragma unroll
        for (int off = 1; off < 256; off <<= 1) {
            unsigned add = (tid + off < 256) ? s_scan[tid + off] : 0u;
            __syncthreads();
            s_scan[tid] += add;
            __syncthreads();
        }
        const unsigned suff = s_scan[tid];
        if (suff >= rem && (suff - mine) < rem) {   // exactly one thread
            s_digit = (unsigned)tid;
            s_newrem = rem - (suff - mine);
        }
        __syncthreads();
        prefix = (prefix << 8) | s_digit;
        rem = s_newrem;
        __syncthreads();
    }
    const unsigned thrkey = prefix;   // exact K-th largest value's key
    // rem = number of threshold-valued elements to include (tie-exact)

    // ---- exp-sum of the top-K negatives
    float lsum = 0.0f;
    if (fast) {
        for (int i = tid; i < cnt; i += BLK) {
            float v = s_cand[i];
            if (ordkey(v) > thrkey) lsum += expf(10.0f * v - m);
        }
    } else {
        for (int j = tid; j < N4; j += BLK) {
            float4 v = x4[j];
            int i0 = j << 2;
            float vv[4] = {v.x, v.y, v.z, v.w};
            #pragma unroll
            for (int e = 0; e < 4; ++e) {
                if (i0 + e == t) continue;
                if (ordkey(vv[e]) > thrkey) lsum += expf(10.0f * vv[e] - m);
            }
        }
        for (int i = (N4 << 2) + tid; i < N; i += BLK) {
            if (i == t) continue;
            float v = x[i];
            if (ordkey(v) > thrkey) lsum += expf(10.0f * v - m);
        }
    }
    if (tid == 0) lsum += (float)rem * expf(10.0f * keyval(thrkey) - m);

    s_red[tid] = lsum;
    __syncthreads();
    for (int s = BLK >> 1; s > 0; s >>= 1) {
        if (tid < s) s_red[tid] += s_red[tid + s];
        __syncthreads();
    }
    if (tid == 0) {
        float s0 = 10.0f * s_pos;
        float denom = 2.0f * expf(s0 - m) + s_red[0];
        row_loss[row] = -(s0 - m - logf(denom));
    }
}

__global__ __launch_bounds__(256) void mean_kernel(
    const float* __restrict__ row_loss, float* __restrict__ out, int B)
{
    __shared__ float s[256];
    float a = 0.0f;
    for (int i = threadIdx.x; i < B; i += 256) a += row_loss[i];
    s[threadIdx.x] = a;
    __syncthreads();
    for (int st = 128; st > 0; st >>= 1) {
        if (threadIdx.x < st) s[threadIdx.x] += s[threadIdx.x + st];
        __syncthreads();
    }
    if (threadIdx.x == 0) out[0] = s[0] / (float)B;
}

extern "C" void kernel_launch(void* const* d_in, const int* in_sizes, int n_in,
                              void* d_out, int out_size, void* d_ws, size_t ws_size,
                              hipStream_t stream) {
    const float* logits  = (const float*)d_in[0];
    const int*   targets = (const int*)d_in[1];
    const int B = in_sizes[1];
    const int N = in_sizes[0] / B;
    const int K = (int)(0.01 * (double)(N - 1));   // matches Python int(R*(N-1))

    float* row_loss = (float*)d_ws;
    row_loss_kernel<<<B, BLK, 0, stream>>>(logits, targets, row_loss, N, K);
    mean_kernel<<<1, 256, 0, stream>>>(row_loss, (float*)d_out, B);
}